// Round 1
// baseline (50248.520 us; speedup 1.0000x reference)
//
#include <hip/hip_runtime.h>

#define TPB 256

static constexpr int B_ = 4;
static constexpr int DEG_ = 16;

// ---------------- kernels ----------------

__global__ void deg_kernel(const int* __restrict__ row, float* __restrict__ deg, int E) {
    int e = blockIdx.x * blockDim.x + threadIdx.x;
    if (e < E) atomicAdd(&deg[row[e]], 1.0f);
}

__global__ void norm_kernel(const int* __restrict__ row, const int* __restrict__ col,
                            const float* __restrict__ deg, float* __restrict__ nrm, int E) {
    int e = blockIdx.x * blockDim.x + threadIdx.x;
    if (e >= E) return;
    float dr = deg[row[e]], dc = deg[col[e]];
    float a = dr > 0.f ? rsqrtf(dr) : 0.f;
    float c = dc > 0.f ? rsqrtf(dc) : 0.f;
    nrm[e] = a * c;
}

__global__ void copyneg_kernel(const float* __restrict__ src, float* __restrict__ dst, int n) {
    int i = blockIdx.x * blockDim.x + threadIdx.x;
    if (i < n) dst[i] = -src[i];
}

__global__ void neg_kernel(float* __restrict__ p, int n) {
    int i = blockIdx.x * blockDim.x + threadIdx.x;
    if (i < n) p[i] = -p[i];
}

// out[b, row[e], :] += scale * nrm[e] * x[b, col[e], :]
__global__ void scatter_kernel(const float* __restrict__ x, float* __restrict__ out,
                               const int* __restrict__ row, const int* __restrict__ col,
                               const float* __restrict__ nrm, int E, int N, int F, float scale) {
    int t = blockIdx.x * blockDim.x + threadIdx.x;
    if (t >= E * B_) return;
    int e = t % E;          // e fastest -> coalesced row/col/nrm reads
    int b = t / E;
    int r = row[e], c = col[e];
    float w = scale * nrm[e];
    const float* xs = x + ((size_t)b * N + c) * F;
    float* os = out + ((size_t)b * N + r) * F;
    for (int f = 0; f < F; ++f) atomicAdd(&os[f], w * xs[f]);
}

// out[row, g] (+)= sum_f T[row, f] * W[f, g]  (+ optional bias, relu)
__global__ void nodegemm_kernel(const float* __restrict__ T, const float* __restrict__ W,
                                float* __restrict__ out, int rows, int F, int G,
                                int accumulate, const float* __restrict__ bias, int relu) {
    extern __shared__ float sW[];
    int tid = threadIdx.x;
    for (int i = tid; i < F * G; i += blockDim.x) sW[i] = W[i];
    __syncthreads();
    int idx = blockIdx.x * blockDim.x + tid;
    if (idx >= rows * G) return;
    int r = idx / G, g = idx % G;
    const float* trow = T + (size_t)r * F;
    float acc = accumulate ? out[idx] : 0.f;
    for (int f = 0; f < F; ++f) acc += trow[f] * sW[f * G + g];
    if (bias) acc += bias[g];
    if (relu) acc = fmaxf(acc, 0.f);
    out[idx] = acc;
}

// out[b, n, f] = sum_{k<3} w[n,k] * in[b, idx[n,k], f]
__global__ void pool_kernel(const float* __restrict__ in, float* __restrict__ out,
                            const int* __restrict__ idx, const float* __restrict__ w,
                            int Nin, int Nout, int F) {
    int t = blockIdx.x * blockDim.x + threadIdx.x;
    if (t >= B_ * Nout * F) return;
    int f = t % F;
    int n = (t / F) % Nout;
    int b = t / (F * Nout);
    float acc = 0.f;
    for (int k = 0; k < 3; ++k) {
        int src = idx[n * 3 + k];
        acc += w[n * 3 + k] * in[((size_t)b * Nin + src) * F + f];
    }
    out[((size_t)b * Nout + n) * F + f] = acc;
}

// z[b, g] = relu(sum_i h[b, i] * W[i, g] + bias[g]);  h: (B, 8192), W: (8192, 64)
__global__ void dense_enc_kernel(const float* __restrict__ h, const float* __restrict__ W,
                                 const float* __restrict__ bias, float* __restrict__ z) {
    int b = blockIdx.x >> 6;
    int g = blockIdx.x & 63;
    int tid = threadIdx.x;
    float acc = 0.f;
    for (int i = tid; i < 8192; i += 256) acc += h[b * 8192 + i] * W[(size_t)i * 64 + g];
    __shared__ float red[256];
    red[tid] = acc;
    __syncthreads();
    for (int sft = 128; sft > 0; sft >>= 1) {
        if (tid < sft) red[tid] += red[tid + sft];
        __syncthreads();
    }
    if (tid == 0) z[b * 64 + g] = fmaxf(red[0] + bias[g], 0.f);
}

// out[b, j] = relu(sum_k z[b,k] * W[k, j] + bias[j]);  W: (64, 8192)
__global__ void dense_dec_kernel(const float* __restrict__ z, const float* __restrict__ W,
                                 const float* __restrict__ bias, float* __restrict__ out) {
    int t = blockIdx.x * blockDim.x + threadIdx.x;
    if (t >= B_ * 8192) return;
    int b = t / 8192, j = t % 8192;
    float acc = bias[j];
    for (int k = 0; k < 64; ++k) acc += z[b * 64 + k] * W[(size_t)k * 8192 + j];
    out[t] = fmaxf(acc, 0.f);
}

// ---------------- host ----------------

static inline unsigned cdivu(size_t a, size_t b) { return (unsigned)((a + b - 1) / b); }

extern "C" void kernel_launch(void* const* d_in, const int* in_sizes, int n_in,
                              void* d_out, int out_size, void* d_ws, size_t ws_size,
                              hipStream_t stream) {
    (void)in_sizes; (void)n_in; (void)out_size; (void)ws_size;
    hipStream_t s = stream;

    static const int NS_[5] = {65536, 16384, 4096, 1024, 256};
    static const int FEa[5] = {3, 16, 16, 16, 32};
    static const int FDa[6] = {32, 16, 16, 16, 16, 3};

    const float* x = (const float*)d_in[0];
    const int* ei[4];
    for (int l = 0; l < 4; ++l) ei[l] = (const int*)d_in[1 + l];
    const int* down_i[4]; const float* down_w[4];
    const int* up_i[4];   const float* up_w[4];
    for (int i = 0; i < 4; ++i) {
        down_i[i] = (const int*)d_in[6 + 4 * i];
        down_w[i] = (const float*)d_in[7 + 4 * i];
        up_i[i]   = (const int*)d_in[8 + 4 * i];
        up_w[i]   = (const float*)d_in[9 + 4 * i];
    }
    const float* encW[4]; const float* encB[4];
    for (int i = 0; i < 4; ++i) {
        encW[i] = (const float*)d_in[22 + 2 * i];
        encB[i] = (const float*)d_in[23 + 2 * i];
    }
    const float* decW[5];
    for (int i = 0; i < 5; ++i) decW[i] = (const float*)d_in[30 + i];
    const float* decB[4];
    for (int i = 0; i < 4; ++i) decB[i] = (const float*)d_in[35 + i];
    const float* enc_w = (const float*)d_in[39];
    const float* enc_b = (const float*)d_in[40];
    const float* dec_w = (const float*)d_in[41];
    const float* dec_b = (const float*)d_in[42];

    // workspace layout (floats); needs ~70 MB
    float* ws = (float*)d_ws;
    size_t off = 0;
    const size_t SLOT = (size_t)B_ * 65536 * 16;  // 4,194,304 floats
    float* S0 = ws + off; off += SLOT;
    float* S1 = ws + off; off += SLOT;
    float* S2 = ws + off; off += SLOT;
    float* S3 = ws + off; off += SLOT;
    float* deg = ws + off; off += 65536;
    float* nrm[4];
    for (int l = 0; l < 4; ++l) { nrm[l] = ws + off; off += (size_t)DEG_ * NS_[l]; }
    float* zbuf = ws + off; off += 256;

    // ---- norms for levels 0..3 ----
    for (int l = 0; l < 4; ++l) {
        int N = NS_[l], E = DEG_ * N;
        hipMemsetAsync(deg, 0, (size_t)N * sizeof(float), s);
        deg_kernel<<<cdivu(E, TPB), TPB, 0, s>>>(ei[l], deg, E);
        norm_kernel<<<cdivu(E, TPB), TPB, 0, s>>>(ei[l], ei[l] + E, deg, nrm[l], E);
    }

    auto gemm = [&](const float* T, const float* W, float* out, int rows, int F, int G,
                    int acc, const float* bias, int relu) {
        int total = rows * G;
        nodegemm_kernel<<<cdivu(total, TPB), TPB, (size_t)F * G * sizeof(float), s>>>(
            T, W, out, rows, F, G, acc, bias, relu);
    };

    // Chebyshev conv: xin (B,N,F) -> out (B,N,G); Q,R scratch (>= B*N*F floats)
    auto cheb = [&](const float* xin, const float* Wk, const float* bias, int relu,
                    const int* eiP, const float* nr, int N, int F, int G,
                    float* Q, float* R, float* out) {
        int E = DEG_ * N;
        const int* row = eiP;
        const int* col = eiP + E;
        int rows = B_ * N;
        size_t ne = (size_t)rows * F;
        unsigned sgrid = cdivu((size_t)E * B_, TPB);
        // k = 0: out = x @ W0
        gemm(xin, Wk, out, rows, F, G, 0, nullptr, 0);
        // k = 1: Tx1 = L x  (into Q)
        hipMemsetAsync(Q, 0, ne * sizeof(float), s);
        scatter_kernel<<<sgrid, TPB, 0, s>>>(xin, Q, row, col, nr, E, N, F, 1.0f);
        gemm(Q, Wk + (size_t)1 * F * G, out, rows, F, G, 1, nullptr, 0);
        // k = 2: Tx2 = 2 L Tx1 - Tx0  (into R)
        copyneg_kernel<<<cdivu(ne, TPB), TPB, 0, s>>>(xin, R, (int)ne);
        scatter_kernel<<<sgrid, TPB, 0, s>>>(Q, R, row, col, nr, E, N, F, 2.0f);
        gemm(R, Wk + (size_t)2 * F * G, out, rows, F, G, 1, nullptr, 0);
        // k = 3..5: in-place over T_{k-2}
        float* Tp = Q;  // T_{k-2}
        float* Tc = R;  // T_{k-1}
        for (int k = 3; k < 6; ++k) {
            neg_kernel<<<cdivu(ne, TPB), TPB, 0, s>>>(Tp, (int)ne);
            scatter_kernel<<<sgrid, TPB, 0, s>>>(Tc, Tp, row, col, nr, E, N, F, 2.0f);
            int last = (k == 5);
            gemm(Tp, Wk + (size_t)k * F * G, out, rows, F, G, 1,
                 last ? bias : nullptr, last ? relu : 0);
            float* t = Tp; Tp = Tc; Tc = t;
        }
    };

    // ---- encoder ----
    const float* h = x;
    for (int i = 0; i < 4; ++i) {
        cheb(h, encW[i], encB[i], 1, ei[i], nrm[i], NS_[i], FEa[i], FEa[i + 1], S0, S1, S2);
        pool_kernel<<<cdivu((size_t)B_ * NS_[i + 1] * FEa[i + 1], TPB), TPB, 0, s>>>(
            S2, S3, down_i[i], down_w[i], NS_[i], NS_[i + 1], FEa[i + 1]);
        h = S3;
    }

    // ---- latent ----
    dense_enc_kernel<<<B_ * 64, 256, 0, s>>>(S3, enc_w, enc_b, zbuf);
    dense_dec_kernel<<<cdivu((size_t)B_ * 8192, TPB), TPB, 0, s>>>(zbuf, dec_w, dec_b, S3);

    // ---- decoder ----
    for (int i = 0; i < 4; ++i) {
        int lvl = 3 - i;
        pool_kernel<<<cdivu((size_t)B_ * NS_[lvl] * FDa[i], TPB), TPB, 0, s>>>(
            S3, S2, up_i[lvl], up_w[lvl], NS_[lvl + 1], NS_[lvl], FDa[i]);
        cheb(S2, decW[i], decB[i], 1, ei[lvl], nrm[lvl], NS_[lvl], FDa[i], FDa[i + 1],
             S0, S1, S3);
    }
    // final conv: no bias, no relu -> d_out
    cheb(S3, decW[4], nullptr, 0, ei[0], nrm[0], NS_[0], FDa[4], FDa[5],
         S0, S1, (float*)d_out);
}

// Round 2
// 2051.707 us; speedup vs baseline: 24.4911x; 24.4911x over previous
//
#include <hip/hip_runtime.h>

#define TPB 256

static constexpr int B_ = 4;
static constexpr int DEG_ = 16;

// ---------------- CSR build kernels ----------------

__global__ void cnt_kernel(const int* __restrict__ row, int* __restrict__ cnt, int E) {
    int e = blockIdx.x * blockDim.x + threadIdx.x;
    if (e < E) atomicAdd(&cnt[row[e]], 1);
}

__global__ void dis_kernel(const int* __restrict__ cnt, float* __restrict__ dis, int N) {
    int n = blockIdx.x * blockDim.x + threadIdx.x;
    if (n < N) dis[n] = cnt[n] > 0 ? rsqrtf((float)cnt[n]) : 0.f;
}

// single-block exclusive scan; N divisible by 256
__global__ void scan_kernel(const int* __restrict__ cnt, int* __restrict__ rowptr, int N, int E) {
    __shared__ int ssum[256];
    __shared__ int sscan[256];
    int tid = threadIdx.x;
    int chunk = N / 256;
    int base = tid * chunk;
    int sum = 0;
    for (int i = 0; i < chunk; ++i) sum += cnt[base + i];
    ssum[tid] = sum;
    __syncthreads();
    if (tid == 0) {
        int a = 0;
        for (int i = 0; i < 256; ++i) { sscan[i] = a; a += ssum[i]; }
    }
    __syncthreads();
    int run = sscan[tid];
    for (int i = 0; i < chunk; ++i) { rowptr[base + i] = run; run += cnt[base + i]; }
    if (tid == 255) rowptr[N] = E;
}

__global__ void fill_kernel(const int* __restrict__ row, const int* __restrict__ col,
                            const int* __restrict__ rowptr, int* __restrict__ cur,
                            const float* __restrict__ dis, int* __restrict__ ccol,
                            float* __restrict__ cw, int E) {
    int e = blockIdx.x * blockDim.x + threadIdx.x;
    if (e >= E) return;
    int r = row[e], c = col[e];
    int pos = rowptr[r] + atomicAdd(&cur[r], 1);
    ccol[pos] = c;
    cw[pos] = dis[r] * dis[c];
}

// ---------------- fused Chebyshev sweep ----------------
// FIRST:  T1 = L x (gather Tc=x) -> write Tio;  out = x@W0 + T1@W1   (out write-only)
// else:   Tk = 2*L*Tc - Tio_self -> write Tio in place;  out += Tk@Wk
// LAST:   additionally + bias, relu
template<int F, int G, bool FIRST, bool LAST>
__global__ __launch_bounds__(256) void cheb_sweep(
    const float* __restrict__ Tc, float* __restrict__ Tio,
    const int* __restrict__ rowptr, const int* __restrict__ ccol,
    const float* __restrict__ cw, const float* __restrict__ Wk,
    const float* __restrict__ bias, float* __restrict__ out, int N, int relu)
{
    constexpr int WSZ = (FIRST ? 2 : 1) * F * G;
    __shared__ float sW[WSZ];
    for (int i = threadIdx.x; i < WSZ; i += 256) sW[i] = Wk[i];
    __syncthreads();
    int t = blockIdx.x * 256 + threadIdx.x;
    if (t >= B_ * N) return;
    int b = t / N;
    int r = t - b * N;
    const float alpha = FIRST ? 1.0f : 2.0f;

    float tv[F];
    if (FIRST) {
        #pragma unroll
        for (int f = 0; f < F; ++f) tv[f] = 0.f;
    } else {
        const float* self = Tio + (size_t)t * F;
        #pragma unroll
        for (int f = 0; f < F; ++f) tv[f] = -self[f];
    }
    const float* base = Tc + (size_t)b * N * F;
    int beg = rowptr[r], end = rowptr[r + 1];
    for (int j = beg; j < end; ++j) {
        int c = ccol[j];
        float w = alpha * cw[j];
        const float* src = base + (size_t)c * F;
        if constexpr (F % 4 == 0) {
            #pragma unroll
            for (int f4 = 0; f4 < F / 4; ++f4) {
                float4 v = reinterpret_cast<const float4*>(src)[f4];
                tv[4 * f4 + 0] += w * v.x;
                tv[4 * f4 + 1] += w * v.y;
                tv[4 * f4 + 2] += w * v.z;
                tv[4 * f4 + 3] += w * v.w;
            }
        } else {
            #pragma unroll
            for (int f = 0; f < F; ++f) tv[f] += w * src[f];
        }
    }
    {
        float* dst = Tio + (size_t)t * F;
        #pragma unroll
        for (int f = 0; f < F; ++f) dst[f] = tv[f];
    }

    float acc[G];
    float* orow = out + (size_t)t * G;
    if (FIRST) {
        const float* xs = base + (size_t)r * F;
        #pragma unroll
        for (int g = 0; g < G; ++g) acc[g] = 0.f;
        #pragma unroll
        for (int f = 0; f < F; ++f) {
            float xv = xs[f];
            #pragma unroll
            for (int g = 0; g < G; ++g) acc[g] += xv * sW[f * G + g];
        }
        #pragma unroll
        for (int f = 0; f < F; ++f) {
            float tvf = tv[f];
            #pragma unroll
            for (int g = 0; g < G; ++g) acc[g] += tvf * sW[F * G + f * G + g];
        }
    } else {
        #pragma unroll
        for (int g = 0; g < G; ++g) acc[g] = orow[g];
        #pragma unroll
        for (int f = 0; f < F; ++f) {
            float tvf = tv[f];
            #pragma unroll
            for (int g = 0; g < G; ++g) acc[g] += tvf * sW[f * G + g];
        }
    }
    if (LAST) {
        if (bias) {
            #pragma unroll
            for (int g = 0; g < G; ++g) acc[g] += bias[g];
        }
        if (relu) {
            #pragma unroll
            for (int g = 0; g < G; ++g) acc[g] = fmaxf(acc[g], 0.f);
        }
    }
    #pragma unroll
    for (int g = 0; g < G; ++g) orow[g] = acc[g];
}

// ---------------- pool / dense ----------------

__global__ void pool_kernel(const float* __restrict__ in, float* __restrict__ out,
                            const int* __restrict__ idx, const float* __restrict__ w,
                            int Nin, int Nout, int F) {
    int t = blockIdx.x * blockDim.x + threadIdx.x;
    if (t >= B_ * Nout * F) return;
    int f = t % F;
    int n = (t / F) % Nout;
    int b = t / (F * Nout);
    float acc = 0.f;
    for (int k = 0; k < 3; ++k) {
        int src = idx[n * 3 + k];
        acc += w[n * 3 + k] * in[((size_t)b * Nin + src) * F + f];
    }
    out[((size_t)b * Nout + n) * F + f] = acc;
}

__global__ void dense_enc_kernel(const float* __restrict__ h, const float* __restrict__ W,
                                 const float* __restrict__ bias, float* __restrict__ z) {
    int b = blockIdx.x >> 6;
    int g = blockIdx.x & 63;
    int tid = threadIdx.x;
    float acc = 0.f;
    for (int i = tid; i < 8192; i += 256) acc += h[b * 8192 + i] * W[(size_t)i * 64 + g];
    __shared__ float red[256];
    red[tid] = acc;
    __syncthreads();
    for (int sft = 128; sft > 0; sft >>= 1) {
        if (tid < sft) red[tid] += red[tid + sft];
        __syncthreads();
    }
    if (tid == 0) z[b * 64 + g] = fmaxf(red[0] + bias[g], 0.f);
}

__global__ void dense_dec_kernel(const float* __restrict__ z, const float* __restrict__ W,
                                 const float* __restrict__ bias, float* __restrict__ out) {
    int t = blockIdx.x * blockDim.x + threadIdx.x;
    if (t >= B_ * 8192) return;
    int b = t / 8192, j = t % 8192;
    float acc = bias[j];
    for (int k = 0; k < 64; ++k) acc += z[b * 64 + k] * W[(size_t)k * 8192 + j];
    out[t] = fmaxf(acc, 0.f);
}

// ---------------- host ----------------

static inline unsigned cdivu(size_t a, size_t b) { return (unsigned)((a + b - 1) / b); }

template<int F, int G>
static void run_cheb(const float* Iin, float* I, float* Q, float* out,
                     const float* Wk, const float* bias, int relu,
                     const int* rp, const int* cc, const float* cwp, int N, hipStream_t s) {
    // Iin: input data pointer (== I except for the very first conv where it's a copy target's src)
    const size_t FG = (size_t)F * G;
    unsigned g = cdivu((size_t)B_ * N, 256);
    cheb_sweep<F, G, true, false><<<g, 256, 0, s>>>(Iin, Q, rp, cc, cwp, Wk, nullptr, out, N, 0);
    cheb_sweep<F, G, false, false><<<g, 256, 0, s>>>(Q, I, rp, cc, cwp, Wk + 2 * FG, nullptr, out, N, 0);
    cheb_sweep<F, G, false, false><<<g, 256, 0, s>>>(I, Q, rp, cc, cwp, Wk + 3 * FG, nullptr, out, N, 0);
    cheb_sweep<F, G, false, false><<<g, 256, 0, s>>>(Q, I, rp, cc, cwp, Wk + 4 * FG, nullptr, out, N, 0);
    cheb_sweep<F, G, false, true><<<g, 256, 0, s>>>(I, Q, rp, cc, cwp, Wk + 5 * FG, bias, out, N, relu);
}

extern "C" void kernel_launch(void* const* d_in, const int* in_sizes, int n_in,
                              void* d_out, int out_size, void* d_ws, size_t ws_size,
                              hipStream_t stream) {
    (void)in_sizes; (void)n_in; (void)out_size; (void)ws_size;
    hipStream_t s = stream;

    static const int NS_[5] = {65536, 16384, 4096, 1024, 256};

    const float* x = (const float*)d_in[0];
    const int* ei[4];
    for (int l = 0; l < 4; ++l) ei[l] = (const int*)d_in[1 + l];
    const int* down_i[4]; const float* down_w[4];
    const int* up_i[4];   const float* up_w[4];
    for (int i = 0; i < 4; ++i) {
        down_i[i] = (const int*)d_in[6 + 4 * i];
        down_w[i] = (const float*)d_in[7 + 4 * i];
        up_i[i]   = (const int*)d_in[8 + 4 * i];
        up_w[i]   = (const float*)d_in[9 + 4 * i];
    }
    const float* encW[4]; const float* encB[4];
    for (int i = 0; i < 4; ++i) {
        encW[i] = (const float*)d_in[22 + 2 * i];
        encB[i] = (const float*)d_in[23 + 2 * i];
    }
    const float* decW[5];
    for (int i = 0; i < 5; ++i) decW[i] = (const float*)d_in[30 + i];
    const float* decB[4];
    for (int i = 0; i < 4; ++i) decB[i] = (const float*)d_in[35 + i];
    const float* enc_w = (const float*)d_in[39];
    const float* enc_b = (const float*)d_in[40];
    const float* dec_w = (const float*)d_in[41];
    const float* dec_b = (const float*)d_in[42];

    // ---- workspace layout (floats) ----
    float* ws = (float*)d_ws;
    size_t off = 0;
    const size_t SLOT = (size_t)B_ * 65536 * 16;  // 4,194,304 floats (16 MB)
    float* BA = ws + off; off += SLOT;
    float* BB = ws + off; off += SLOT;
    float* BQ = ws + off; off += SLOT;
    int* rowptr[4]; int* ccol[4]; float* cwz[4];
    for (int l = 0; l < 4; ++l) {
        int N = NS_[l], E = DEG_ * N;
        rowptr[l] = (int*)(ws + off); off += (size_t)N + 4;
        ccol[l]   = (int*)(ws + off); off += (size_t)E;
        cwz[l]    = ws + off;         off += (size_t)E;
    }
    int* cnt = (int*)(ws + off); off += 65536;
    float* dis = ws + off; off += 65536;
    float* zbuf = ws + off; off += 256;

    // ---- build CSR + norms for levels 0..3 ----
    for (int l = 0; l < 4; ++l) {
        int N = NS_[l], E = DEG_ * N;
        const int* row = ei[l];
        const int* col = ei[l] + E;
        hipMemsetAsync(cnt, 0, (size_t)N * sizeof(int), s);
        cnt_kernel<<<cdivu(E, TPB), TPB, 0, s>>>(row, cnt, E);
        dis_kernel<<<cdivu(N, TPB), TPB, 0, s>>>(cnt, dis, N);
        scan_kernel<<<1, 256, 0, s>>>(cnt, rowptr[l], N, E);
        hipMemsetAsync(cnt, 0, (size_t)N * sizeof(int), s);
        fill_kernel<<<cdivu(E, TPB), TPB, 0, s>>>(row, col, rowptr[l], cnt, dis,
                                                  ccol[l], cwz[l], E);
    }

    // ---- encoder ----
    // copy x into BA (conv clobbers its input; inputs must not be mutated)
    hipMemcpyAsync(BA, x, (size_t)B_ * 65536 * 3 * sizeof(float),
                   hipMemcpyDeviceToDevice, s);
    // conv0: 3 -> 16
    run_cheb<3, 16>(BA, BA, BQ, BB, encW[0], encB[0], 1,
                    rowptr[0], ccol[0], cwz[0], NS_[0], s);
    pool_kernel<<<cdivu((size_t)B_ * NS_[1] * 16, TPB), TPB, 0, s>>>(
        BB, BA, down_i[0], down_w[0], NS_[0], NS_[1], 16);
    // conv1: 16 -> 16
    run_cheb<16, 16>(BA, BA, BQ, BB, encW[1], encB[1], 1,
                     rowptr[1], ccol[1], cwz[1], NS_[1], s);
    pool_kernel<<<cdivu((size_t)B_ * NS_[2] * 16, TPB), TPB, 0, s>>>(
        BB, BA, down_i[1], down_w[1], NS_[1], NS_[2], 16);
    // conv2: 16 -> 16
    run_cheb<16, 16>(BA, BA, BQ, BB, encW[2], encB[2], 1,
                     rowptr[2], ccol[2], cwz[2], NS_[2], s);
    pool_kernel<<<cdivu((size_t)B_ * NS_[3] * 16, TPB), TPB, 0, s>>>(
        BB, BA, down_i[2], down_w[2], NS_[2], NS_[3], 16);
    // conv3: 16 -> 32
    run_cheb<16, 32>(BA, BA, BQ, BB, encW[3], encB[3], 1,
                     rowptr[3], ccol[3], cwz[3], NS_[3], s);
    pool_kernel<<<cdivu((size_t)B_ * NS_[4] * 32, TPB), TPB, 0, s>>>(
        BB, BA, down_i[3], down_w[3], NS_[3], NS_[4], 32);

    // ---- latent ----
    dense_enc_kernel<<<B_ * 64, 256, 0, s>>>(BA, enc_w, enc_b, zbuf);
    dense_dec_kernel<<<cdivu((size_t)B_ * 8192, TPB), TPB, 0, s>>>(zbuf, dec_w, dec_b, BB);

    // ---- decoder ----
    // i=0: lvl 3, 32 -> 16
    pool_kernel<<<cdivu((size_t)B_ * NS_[3] * 32, TPB), TPB, 0, s>>>(
        BB, BA, up_i[3], up_w[3], NS_[4], NS_[3], 32);
    run_cheb<32, 16>(BA, BA, BQ, BB, decW[0], decB[0], 1,
                     rowptr[3], ccol[3], cwz[3], NS_[3], s);
    // i=1: lvl 2, 16 -> 16
    pool_kernel<<<cdivu((size_t)B_ * NS_[2] * 16, TPB), TPB, 0, s>>>(
        BB, BA, up_i[2], up_w[2], NS_[3], NS_[2], 16);
    run_cheb<16, 16>(BA, BA, BQ, BB, decW[1], decB[1], 1,
                     rowptr[2], ccol[2], cwz[2], NS_[2], s);
    // i=2: lvl 1, 16 -> 16
    pool_kernel<<<cdivu((size_t)B_ * NS_[1] * 16, TPB), TPB, 0, s>>>(
        BB, BA, up_i[1], up_w[1], NS_[2], NS_[1], 16);
    run_cheb<16, 16>(BA, BA, BQ, BB, decW[2], decB[2], 1,
                     rowptr[1], ccol[1], cwz[1], NS_[1], s);
    // i=3: lvl 0, 16 -> 16
    pool_kernel<<<cdivu((size_t)B_ * NS_[0] * 16, TPB), TPB, 0, s>>>(
        BB, BA, up_i[0], up_w[0], NS_[1], NS_[0], 16);
    run_cheb<16, 16>(BA, BA, BQ, BB, decW[3], decB[3], 1,
                     rowptr[0], ccol[0], cwz[0], NS_[0], s);
    // final conv: lvl 0, 16 -> 3, no bias, no relu, output -> d_out
    run_cheb<16, 3>(BB, BB, BQ, (float*)d_out, decW[4], nullptr, 0,
                    rowptr[0], ccol[0], cwz[0], NS_[0], s);
}

// Round 3
// 1887.783 us; speedup vs baseline: 26.6177x; 1.0868x over previous
//
#include <hip/hip_runtime.h>

#define TPB 256

static constexpr int B_ = 4;
static constexpr int DEG_ = 16;

// level bases into the packed count array (sum = 87040 = 85 * 1024)
static constexpr int LB0 = 0, LB1 = 65536, LB2 = 81920, LB3 = 86016, LB4 = 87040;
// cumulative edge counts
static constexpr int CE0 = 0, CE1 = 1048576, CE2 = 1310720, CE3 = 1376256, CE4 = 1392640;

// ---------------- CSR build kernels ----------------

__global__ void cnt_kernel(const int* __restrict__ row, int* __restrict__ cnt, int E) {
    int e = blockIdx.x * blockDim.x + threadIdx.x;
    if (e < E) atomicAdd(&cnt[row[e]], 1);
}

// per-block scan: 85 blocks x 1024 elements (256 threads x 4)
__global__ void scanA_kernel(const int* __restrict__ cnt, int* __restrict__ partial,
                             int* __restrict__ bsum) {
    __shared__ int sdata[256];
    int tid = threadIdx.x;
    int base = blockIdx.x * 1024 + tid * 4;
    int v0 = cnt[base], v1 = cnt[base + 1], v2 = cnt[base + 2], v3 = cnt[base + 3];
    int tsum = v0 + v1 + v2 + v3;
    sdata[tid] = tsum;
    __syncthreads();
    for (int ofs = 1; ofs < 256; ofs <<= 1) {
        int x = (tid >= ofs) ? sdata[tid - ofs] : 0;
        __syncthreads();
        sdata[tid] += x;
        __syncthreads();
    }
    int excl = sdata[tid] - tsum;
    partial[base] = excl;         excl += v0;
    partial[base + 1] = excl;     excl += v1;
    partial[base + 2] = excl;     excl += v2;
    partial[base + 3] = excl;
    if (tid == 255) bsum[blockIdx.x] = sdata[255];
}

// exclusive scan of <=128 block sums, in place
__global__ void scanB_kernel(int* __restrict__ bsum, int nb) {
    __shared__ int s[128];
    int tid = threadIdx.x;
    int v = tid < nb ? bsum[tid] : 0;
    s[tid] = v;
    __syncthreads();
    for (int ofs = 1; ofs < 128; ofs <<= 1) {
        int x = (tid >= ofs) ? s[tid - ofs] : 0;
        __syncthreads();
        s[tid] += x;
        __syncthreads();
    }
    if (tid < nb) bsum[tid] = s[tid] - v;
}

// apply block offsets, de-bias by per-level cumulative edges, write rowptrs
__global__ void scanC_kernel(const int* __restrict__ partial, const int* __restrict__ bsum,
                             int* __restrict__ rp0, int* __restrict__ rp1,
                             int* __restrict__ rp2, int* __restrict__ rp3) {
    int i = blockIdx.x * blockDim.x + threadIdx.x;
    if (i >= LB4) return;
    int g = partial[i] + bsum[i >> 10];
    if (i < LB1)      rp0[i - LB0] = g - CE0;
    else if (i < LB2) rp1[i - LB1] = g - CE1;
    else if (i < LB3) rp2[i - LB2] = g - CE2;
    else              rp3[i - LB3] = g - CE3;
    if (i == 0) {
        rp0[LB1 - LB0] = CE1 - CE0;
        rp1[LB2 - LB1] = CE2 - CE1;
        rp2[LB3 - LB2] = CE3 - CE2;
        rp3[LB4 - LB3] = CE4 - CE3;
    }
}

__global__ void fill_kernel(const int* __restrict__ row, const int* __restrict__ col,
                            const int* __restrict__ rowptr, int* __restrict__ cur,
                            const int* __restrict__ cnt, int* __restrict__ ccol,
                            float* __restrict__ cw, int E) {
    int e = blockIdx.x * blockDim.x + threadIdx.x;
    if (e >= E) return;
    int r = row[e], c = col[e];
    int pos = rowptr[r] + atomicAdd(&cur[r], 1);
    float dr = cnt[r] > 0 ? rsqrtf((float)cnt[r]) : 0.f;
    float dc = cnt[c] > 0 ? rsqrtf((float)cnt[c]) : 0.f;
    ccol[pos] = c;
    cw[pos] = dr * dc;
}

// ---------------- fused Chebyshev sweep ----------------
// FIRST:  T1 = L x (gather Tc=x) -> write Tio;  out = x@W0 + T1@W1   (out write-only)
// else:   Tk = 2*L*Tc - Tio_self -> write Tio in place;  out += Tk@Wk
// LAST:   additionally + bias, relu
template<int F, int G, bool FIRST, bool LAST>
__global__ __launch_bounds__(256) void cheb_sweep(
    const float* __restrict__ Tc, float* __restrict__ Tio,
    const int* __restrict__ rowptr, const int* __restrict__ ccol,
    const float* __restrict__ cw, const float* __restrict__ Wk,
    const float* __restrict__ bias, float* __restrict__ out, int N, int relu)
{
    constexpr int WSZ = (FIRST ? 2 : 1) * F * G;
    __shared__ float sW[WSZ];
    for (int i = threadIdx.x; i < WSZ; i += 256) sW[i] = Wk[i];
    __syncthreads();
    int t = blockIdx.x * 256 + threadIdx.x;
    if (t >= B_ * N) return;
    int b = t / N;
    int r = t - b * N;
    const float alpha = FIRST ? 1.0f : 2.0f;

    float tv[F];
    if (FIRST) {
        #pragma unroll
        for (int f = 0; f < F; ++f) tv[f] = 0.f;
    } else {
        const float* self = Tio + (size_t)t * F;
        #pragma unroll
        for (int f = 0; f < F; ++f) tv[f] = -self[f];
    }
    const float* base = Tc + (size_t)b * N * F;
    int beg = rowptr[r], end = rowptr[r + 1];
    for (int j = beg; j < end; ++j) {
        int c = ccol[j];
        float w = alpha * cw[j];
        const float* src = base + (size_t)c * F;
        if constexpr (F % 4 == 0) {
            #pragma unroll
            for (int f4 = 0; f4 < F / 4; ++f4) {
                float4 v = reinterpret_cast<const float4*>(src)[f4];
                tv[4 * f4 + 0] += w * v.x;
                tv[4 * f4 + 1] += w * v.y;
                tv[4 * f4 + 2] += w * v.z;
                tv[4 * f4 + 3] += w * v.w;
            }
        } else {
            #pragma unroll
            for (int f = 0; f < F; ++f) tv[f] += w * src[f];
        }
    }
    {
        float* dst = Tio + (size_t)t * F;
        #pragma unroll
        for (int f = 0; f < F; ++f) dst[f] = tv[f];
    }

    float acc[G];
    float* orow = out + (size_t)t * G;
    if (FIRST) {
        const float* xs = base + (size_t)r * F;
        #pragma unroll
        for (int g = 0; g < G; ++g) acc[g] = 0.f;
        #pragma unroll
        for (int f = 0; f < F; ++f) {
            float xv = xs[f];
            #pragma unroll
            for (int g = 0; g < G; ++g) acc[g] += xv * sW[f * G + g];
        }
        #pragma unroll
        for (int f = 0; f < F; ++f) {
            float tvf = tv[f];
            #pragma unroll
            for (int g = 0; g < G; ++g) acc[g] += tvf * sW[F * G + f * G + g];
        }
    } else {
        #pragma unroll
        for (int g = 0; g < G; ++g) acc[g] = orow[g];
        #pragma unroll
        for (int f = 0; f < F; ++f) {
            float tvf = tv[f];
            #pragma unroll
            for (int g = 0; g < G; ++g) acc[g] += tvf * sW[f * G + g];
        }
    }
    if (LAST) {
        if (bias) {
            #pragma unroll
            for (int g = 0; g < G; ++g) acc[g] += bias[g];
        }
        if (relu) {
            #pragma unroll
            for (int g = 0; g < G; ++g) acc[g] = fmaxf(acc[g], 0.f);
        }
    }
    #pragma unroll
    for (int g = 0; g < G; ++g) orow[g] = acc[g];
}

// ---------------- pool / dense ----------------

__global__ void pool_kernel(const float* __restrict__ in, float* __restrict__ out,
                            const int* __restrict__ idx, const float* __restrict__ w,
                            int Nin, int Nout, int F) {
    int t = blockIdx.x * blockDim.x + threadIdx.x;
    if (t >= B_ * Nout * F) return;
    int f = t % F;
    int n = (t / F) % Nout;
    int b = t / (F * Nout);
    float acc = 0.f;
    for (int k = 0; k < 3; ++k) {
        int src = idx[n * 3 + k];
        acc += w[n * 3 + k] * in[((size_t)b * Nin + src) * F + f];
    }
    out[((size_t)b * Nout + n) * F + f] = acc;
}

__global__ void dense_enc_kernel(const float* __restrict__ h, const float* __restrict__ W,
                                 const float* __restrict__ bias, float* __restrict__ z) {
    int b = blockIdx.x >> 6;
    int g = blockIdx.x & 63;
    int tid = threadIdx.x;
    float acc = 0.f;
    for (int i = tid; i < 8192; i += 256) acc += h[b * 8192 + i] * W[(size_t)i * 64 + g];
    __shared__ float red[256];
    red[tid] = acc;
    __syncthreads();
    for (int sft = 128; sft > 0; sft >>= 1) {
        if (tid < sft) red[tid] += red[tid + sft];
        __syncthreads();
    }
    if (tid == 0) z[b * 64 + g] = fmaxf(red[0] + bias[g], 0.f);
}

__global__ void dense_dec_kernel(const float* __restrict__ z, const float* __restrict__ W,
                                 const float* __restrict__ bias, float* __restrict__ out) {
    int t = blockIdx.x * blockDim.x + threadIdx.x;
    if (t >= B_ * 8192) return;
    int b = t / 8192, j = t % 8192;
    float acc = bias[j];
    for (int k = 0; k < 64; ++k) acc += z[b * 64 + k] * W[(size_t)k * 8192 + j];
    out[t] = fmaxf(acc, 0.f);
}

// ---------------- host ----------------

static inline unsigned cdivu(size_t a, size_t b) { return (unsigned)((a + b - 1) / b); }

template<int F, int G>
static void run_cheb(const float* Iin, float* I, float* Q, float* out,
                     const float* Wk, const float* bias, int relu,
                     const int* rp, const int* cc, const float* cwp, int N, hipStream_t s) {
    const size_t FG = (size_t)F * G;
    unsigned g = cdivu((size_t)B_ * N, 256);
    cheb_sweep<F, G, true, false><<<g, 256, 0, s>>>(Iin, Q, rp, cc, cwp, Wk, nullptr, out, N, 0);
    cheb_sweep<F, G, false, false><<<g, 256, 0, s>>>(Q, I, rp, cc, cwp, Wk + 2 * FG, nullptr, out, N, 0);
    cheb_sweep<F, G, false, false><<<g, 256, 0, s>>>(I, Q, rp, cc, cwp, Wk + 3 * FG, nullptr, out, N, 0);
    cheb_sweep<F, G, false, false><<<g, 256, 0, s>>>(Q, I, rp, cc, cwp, Wk + 4 * FG, nullptr, out, N, 0);
    cheb_sweep<F, G, false, true><<<g, 256, 0, s>>>(I, Q, rp, cc, cwp, Wk + 5 * FG, bias, out, N, relu);
}

extern "C" void kernel_launch(void* const* d_in, const int* in_sizes, int n_in,
                              void* d_out, int out_size, void* d_ws, size_t ws_size,
                              hipStream_t stream) {
    (void)in_sizes; (void)n_in; (void)out_size; (void)ws_size;
    hipStream_t s = stream;

    static const int NS_[5] = {65536, 16384, 4096, 1024, 256};
    static const int LBa[5] = {LB0, LB1, LB2, LB3, LB4};

    const float* x = (const float*)d_in[0];
    const int* ei[4];
    for (int l = 0; l < 4; ++l) ei[l] = (const int*)d_in[1 + l];
    const int* down_i[4]; const float* down_w[4];
    const int* up_i[4];   const float* up_w[4];
    for (int i = 0; i < 4; ++i) {
        down_i[i] = (const int*)d_in[6 + 4 * i];
        down_w[i] = (const float*)d_in[7 + 4 * i];
        up_i[i]   = (const int*)d_in[8 + 4 * i];
        up_w[i]   = (const float*)d_in[9 + 4 * i];
    }
    const float* encW[4]; const float* encB[4];
    for (int i = 0; i < 4; ++i) {
        encW[i] = (const float*)d_in[22 + 2 * i];
        encB[i] = (const float*)d_in[23 + 2 * i];
    }
    const float* decW[5];
    for (int i = 0; i < 5; ++i) decW[i] = (const float*)d_in[30 + i];
    const float* decB[4];
    for (int i = 0; i < 4; ++i) decB[i] = (const float*)d_in[35 + i];
    const float* enc_w = (const float*)d_in[39];
    const float* enc_b = (const float*)d_in[40];
    const float* dec_w = (const float*)d_in[41];
    const float* dec_b = (const float*)d_in[42];

    // ---- workspace layout (floats) ----
    float* ws = (float*)d_ws;
    size_t off = 0;
    const size_t SLOT = (size_t)B_ * 65536 * 16;  // 4,194,304 floats (16 MB)
    float* BA = ws + off; off += SLOT;
    float* BB = ws + off; off += SLOT;
    float* BQ = ws + off; off += SLOT;
    int* cntAll = (int*)(ws + off); off += LB4;
    int* curAll = (int*)(ws + off); off += LB4;
    int* partial = (int*)(ws + off); off += LB4;
    int* bsum = (int*)(ws + off); off += 128;
    int* rowptr[4]; int* ccol[4]; float* cwz[4];
    for (int l = 0; l < 4; ++l) {
        int N = NS_[l], E = DEG_ * N;
        rowptr[l] = (int*)(ws + off); off += (size_t)N + 4;
        ccol[l]   = (int*)(ws + off); off += (size_t)E;
        cwz[l]    = ws + off;         off += (size_t)E;
    }
    float* zbuf = ws + off; off += 256;

    // ---- build CSR + norms for levels 0..3 ----
    hipMemsetAsync(cntAll, 0, (size_t)LB4 * sizeof(int), s);
    hipMemsetAsync(curAll, 0, (size_t)LB4 * sizeof(int), s);
    for (int l = 0; l < 4; ++l) {
        int E = DEG_ * NS_[l];
        cnt_kernel<<<cdivu(E, TPB), TPB, 0, s>>>(ei[l], cntAll + LBa[l], E);
    }
    scanA_kernel<<<85, 256, 0, s>>>(cntAll, partial, bsum);
    scanB_kernel<<<1, 128, 0, s>>>(bsum, 85);
    scanC_kernel<<<cdivu(LB4, TPB), TPB, 0, s>>>(partial, bsum,
                                                 rowptr[0], rowptr[1], rowptr[2], rowptr[3]);
    for (int l = 0; l < 4; ++l) {
        int E = DEG_ * NS_[l];
        fill_kernel<<<cdivu(E, TPB), TPB, 0, s>>>(ei[l], ei[l] + E, rowptr[l],
                                                  curAll + LBa[l], cntAll + LBa[l],
                                                  ccol[l], cwz[l], E);
    }

    // ---- encoder ----
    hipMemcpyAsync(BA, x, (size_t)B_ * 65536 * 3 * sizeof(float),
                   hipMemcpyDeviceToDevice, s);
    run_cheb<3, 16>(BA, BA, BQ, BB, encW[0], encB[0], 1,
                    rowptr[0], ccol[0], cwz[0], NS_[0], s);
    pool_kernel<<<cdivu((size_t)B_ * NS_[1] * 16, TPB), TPB, 0, s>>>(
        BB, BA, down_i[0], down_w[0], NS_[0], NS_[1], 16);
    run_cheb<16, 16>(BA, BA, BQ, BB, encW[1], encB[1], 1,
                     rowptr[1], ccol[1], cwz[1], NS_[1], s);
    pool_kernel<<<cdivu((size_t)B_ * NS_[2] * 16, TPB), TPB, 0, s>>>(
        BB, BA, down_i[1], down_w[1], NS_[1], NS_[2], 16);
    run_cheb<16, 16>(BA, BA, BQ, BB, encW[2], encB[2], 1,
                     rowptr[2], ccol[2], cwz[2], NS_[2], s);
    pool_kernel<<<cdivu((size_t)B_ * NS_[3] * 16, TPB), TPB, 0, s>>>(
        BB, BA, down_i[2], down_w[2], NS_[2], NS_[3], 16);
    run_cheb<16, 32>(BA, BA, BQ, BB, encW[3], encB[3], 1,
                     rowptr[3], ccol[3], cwz[3], NS_[3], s);
    pool_kernel<<<cdivu((size_t)B_ * NS_[4] * 32, TPB), TPB, 0, s>>>(
        BB, BA, down_i[3], down_w[3], NS_[3], NS_[4], 32);

    // ---- latent ----
    dense_enc_kernel<<<B_ * 64, 256, 0, s>>>(BA, enc_w, enc_b, zbuf);
    dense_dec_kernel<<<cdivu((size_t)B_ * 8192, TPB), TPB, 0, s>>>(zbuf, dec_w, dec_b, BB);

    // ---- decoder ----
    pool_kernel<<<cdivu((size_t)B_ * NS_[3] * 32, TPB), TPB, 0, s>>>(
        BB, BA, up_i[3], up_w[3], NS_[4], NS_[3], 32);
    run_cheb<32, 16>(BA, BA, BQ, BB, decW[0], decB[0], 1,
                     rowptr[3], ccol[3], cwz[3], NS_[3], s);
    pool_kernel<<<cdivu((size_t)B_ * NS_[2] * 16, TPB), TPB, 0, s>>>(
        BB, BA, up_i[2], up_w[2], NS_[3], NS_[2], 16);
    run_cheb<16, 16>(BA, BA, BQ, BB, decW[1], decB[1], 1,
                     rowptr[2], ccol[2], cwz[2], NS_[2], s);
    pool_kernel<<<cdivu((size_t)B_ * NS_[1] * 16, TPB), TPB, 0, s>>>(
        BB, BA, up_i[1], up_w[1], NS_[2], NS_[1], 16);
    run_cheb<16, 16>(BA, BA, BQ, BB, decW[2], decB[2], 1,
                     rowptr[1], ccol[1], cwz[1], NS_[1], s);
    pool_kernel<<<cdivu((size_t)B_ * NS_[0] * 16, TPB), TPB, 0, s>>>(
        BB, BA, up_i[0], up_w[0], NS_[1], NS_[0], 16);
    run_cheb<16, 16>(BA, BA, BQ, BB, decW[3], decB[3], 1,
                     rowptr[0], ccol[0], cwz[0], NS_[0], s);
    run_cheb<16, 3>(BB, BB, BQ, (float*)d_out, decW[4], nullptr, 0,
                    rowptr[0], ccol[0], cwz[0], NS_[0], s);
}